// Round 3
// baseline (386.618 us; speedup 1.0000x reference)
//
#include <hip/hip_runtime.h>
#include <hip/hip_bf16.h>
#include <math.h>

#define BB 64
#define DD 256
#define TT 24
#define NR 289

typedef float f32x4 __attribute__((ext_vector_type(4)));
typedef short bf16x8 __attribute__((ext_vector_type(8)));

// ws layout (bytes)
#define ET_OFF   0ul                     // eT  [64][32][256] bf16 (t>=24 zero)   1,048,576
#define VT_OFF   1048576ul               // vT  [64][304][256] bf16 (n>=289 zero) 9,961,472
#define VBF_OFF  11010048ul              // vbf [64][256][320] bf16 (n>=289 zero) 10,485,760
#define SMAT_OFF 21495808ul              // Smat [4096] f32

// ---- convert e -> eT[i][t][d] bf16, rows t>=24 zeroed
__global__ void conv_e_kernel(const float* __restrict__ e, __hip_bfloat16* __restrict__ eT) {
    int i = blockIdx.x, d = threadIdx.x;
    const float* src = e + ((size_t)i * DD + d) * TT;
    __hip_bfloat16* dst = eT + (size_t)i * 32 * DD + d;
    #pragma unroll
    for (int t = 0; t < 32; ++t) {
        float vv = (t < TT) ? src[t] : 0.f;
        dst[(size_t)t * DD] = __float2bfloat16(vv);
    }
}

// ---- convert v -> vT[j][n][d] and vbf[j][d][n] (both bf16, padded with zeros)
__global__ __launch_bounds__(256) void conv_v_kernel(const float* __restrict__ v,
                                                     __hip_bfloat16* __restrict__ vT,
                                                     __hip_bfloat16* __restrict__ vbf) {
    __shared__ float ld[32][305];   // pitch 305: coprime with 32 -> conflict-free col reads
    int j = blockIdx.x >> 3;
    int dbase = (blockIdx.x & 7) * 32;
    int tid = threadIdx.x;
    const float* vj = v + (size_t)j * DD * NR;
    for (int r = 0; r < 32; ++r) {
        const float* row = vj + (size_t)(dbase + r) * NR;
        ld[r][tid] = row[tid];
        if (tid < 48) {
            int n = 256 + tid;
            ld[r][n] = (n < NR) ? row[n] : 0.f;
        }
    }
    __syncthreads();
    { // vT[j][n][dbase+d], coalesced 32-lane writes
        int d = tid & 31, ng = tid >> 5;
        __hip_bfloat16* base = vT + (size_t)j * 304 * DD + dbase + d;
        for (int n = ng; n < 304; n += 8)
            base[(size_t)n * DD] = __float2bfloat16(ld[d][n]);
    }
    { // vbf[j][dbase+r][n], coalesced
        __hip_bfloat16* base = vbf + ((size_t)j * DD + dbase) * 320;
        for (int idx = tid; idx < 32 * 320; idx += 256) {
            int r = idx / 320, n = idx - r * 320;
            float vv = (n < NR) ? ld[r][n] : 0.f;
            base[(size_t)r * 320 + n] = __float2bfloat16(vv);
        }
    }
}

// ---- one block per (i,j) pair; Smat[j*64+i] = S[i][j]
// LDS = exactly 20480 B (alpha buffer holds bf16 scores, then s_norm, then alpha,
// then the cross-wave LSE scratch) -> 8 blocks/CU.
__global__ __launch_bounds__(256, 8) void pair_kernel(const float* __restrict__ e,
                                                      const __hip_bfloat16* __restrict__ eT,
                                                      const __hip_bfloat16* __restrict__ vT,
                                                      const __hip_bfloat16* __restrict__ vbf,
                                                      float* __restrict__ Smat) {
    __shared__ __align__(16) __hip_bfloat16 alpha[32 * 320];   // 20480 B, XOR-swizzled rows

    const int tid = threadIdx.x;
    const int wave = tid >> 6, lane = tid & 63;
    const int c = lane & 15, g = lane >> 4;
    const int bid = blockIdx.x;
    const int i = bid & 63, j = bid >> 6;

    char* ab = (char*)alpha;

    // zero whole buffer (pad rows 24..31 and cols >=289 must be 0 for GEMM2)
    {
        uint32_t* az = (uint32_t*)alpha;
        #pragma unroll
        for (int q = 0; q < 20; ++q) az[tid + q * 256] = 0u;
    }
    __syncthreads();

    // ================= GEMM1: s[t][n] = sum_d eT[i][t][d] * v[j][d][n] ==========
    const bf16x8* eA = (const bf16x8*)(eT + (size_t)i * 32 * DD);
    bf16x8 a1[2][8];
    #pragma unroll
    for (int m = 0; m < 2; ++m)
        #pragma unroll
        for (int k = 0; k < 8; ++k)
            a1[m][k] = eA[(m * 16 + c) * 32 + k * 4 + g];

    const bf16x8* vB = (const bf16x8*)(vT + (size_t)j * 304 * DD);
    for (int nt = wave; nt < 19; nt += 4) {
        bf16x8 b1[8];
        #pragma unroll
        for (int k = 0; k < 8; ++k)
            b1[k] = vB[(nt * 16 + c) * 32 + k * 4 + g];
        f32x4 acc0 = {0.f, 0.f, 0.f, 0.f}, acc1 = {0.f, 0.f, 0.f, 0.f};
        #pragma unroll
        for (int k = 0; k < 8; ++k) {
            acc0 = __builtin_amdgcn_mfma_f32_16x16x32_bf16(a1[0][k], b1[k], acc0, 0, 0, 0);
            acc1 = __builtin_amdgcn_mfma_f32_16x16x32_bf16(a1[1][k], b1[k], acc1, 0, 0, 0);
        }
        // store scores as bf16 into the swizzled alpha buffer
        #pragma unroll
        for (int r = 0; r < 4; ++r) {
            int t0 = g * 4 + r;
            int b0 = ((t0 * 320 + nt * 16 + c) * 2) ^ ((t0 & 7) << 4);
            *(__hip_bfloat16*)(ab + b0) = __float2bfloat16(acc0[r]);
            int t1 = 16 + g * 4 + r;
            if (t1 < TT) {
                int b1o = ((t1 * 320 + nt * 16 + c) * 2) ^ ((t1 & 7) << 4);
                *(__hip_bfloat16*)(ab + b1o) = __float2bfloat16(acc1[r]);
            }
        }
    }
    __syncthreads();

    // ============ softmax over n, in place on bf16 rows (wave owns 6 t-rows) ====
    #pragma unroll
    for (int tt = 0; tt < 6; ++tt) {
        int t = wave * 6 + tt;
        int base = t * 640, sw = (t & 7) << 4;
        float vls[5];
        #pragma unroll
        for (int k5 = 0; k5 < 5; ++k5) {
            int n = k5 * 64 + lane;
            vls[k5] = (n < NR)
                ? __bfloat162float(*(const __hip_bfloat16*)(ab + ((base + 2 * n) ^ sw)))
                : -INFINITY;
        }
        float m = vls[0];
        #pragma unroll
        for (int k5 = 1; k5 < 5; ++k5) m = fmaxf(m, vls[k5]);
        #pragma unroll
        for (int mk = 32; mk >= 1; mk >>= 1) m = fmaxf(m, __shfl_xor(m, mk, 64));
        float sum = 0.f;
        #pragma unroll
        for (int k5 = 0; k5 < 5; ++k5) { vls[k5] = __expf(vls[k5] - m); sum += vls[k5]; }
        #pragma unroll
        for (int mk = 32; mk >= 1; mk >>= 1) sum += __shfl_xor(sum, mk, 64);
        float inv = 1.f / sum;
        #pragma unroll
        for (int k5 = 0; k5 < 5; ++k5) {
            int n = k5 * 64 + lane;
            if (n < NR)
                *(__hip_bfloat16*)(ab + ((base + 2 * n) ^ sw)) = __float2bfloat16(vls[k5] * inv);
        }
    }
    __syncthreads();

    // ====== softmax over t of G1*s_norm, in place per column (thread <-> n) =====
    for (int p = 0; p < 2; ++p) {
        int n = p * 256 + tid;
        if (n < NR) {
            float vals[TT];
            #pragma unroll
            for (int t = 0; t < TT; ++t)
                vals[t] = __bfloat162float(
                    *(const __hip_bfloat16*)(ab + ((t * 640 + 2 * n) ^ ((t & 7) << 4))));
            float m = vals[0];
            #pragma unroll
            for (int t = 1; t < TT; ++t) m = fmaxf(m, vals[t]);
            m *= 4.0f;
            float sum = 0.f;
            #pragma unroll
            for (int t = 0; t < TT; ++t) { vals[t] = __expf(4.0f * vals[t] - m); sum += vals[t]; }
            float inv = 1.f / sum;
            #pragma unroll
            for (int t = 0; t < TT; ++t)
                *(__hip_bfloat16*)(ab + ((t * 640 + 2 * n) ^ ((t & 7) << 4))) =
                    __float2bfloat16(vals[t] * inv);
        }
    }
    __syncthreads();

    // ====== GEMM2: c[t][d] = sum_n alpha[t][n]*v[d][n]; fused epilogue ==========
    bf16x8 a2[2][10];
    {
        #pragma unroll
        for (int m = 0; m < 2; ++m) {
            int t = m * 16 + c;
            int sw = (t & 7) << 4;
            #pragma unroll
            for (int k = 0; k < 10; ++k) {
                int boff = (t * 640 + k * 64 + g * 16) ^ sw;
                a2[m][k] = *(const bf16x8*)(ab + boff);
            }
        }
    }
    const bf16x8* vB2 = (const bf16x8*)(vbf + (size_t)j * DD * 320);
    const float* ei = e + (size_t)i * DD * TT;

    float mrun = -INFINITY, srun = 0.f;
    for (int q = 0; q < 4; ++q) {
        int nt = wave + q * 4;   // d-tile
        bf16x8 b2[10];
        #pragma unroll
        for (int k = 0; k < 10; ++k)
            b2[k] = vB2[(nt * 16 + c) * 40 + k * 4 + g];
        f32x4 acc0 = {0.f, 0.f, 0.f, 0.f}, acc1 = {0.f, 0.f, 0.f, 0.f};
        #pragma unroll
        for (int k = 0; k < 10; ++k) {
            acc0 = __builtin_amdgcn_mfma_f32_16x16x32_bf16(a2[0][k], b2[k], acc0, 0, 0, 0);
            acc1 = __builtin_amdgcn_mfma_f32_16x16x32_bf16(a2[1][k], b2[k], acc1, 0, 0, 0);
        }
        // epilogue: cosine over t for this lane's d column
        int d = nt * 16 + c;
        const float* ed = ei + d * TT;
        float dot = 0.f, cn2 = 0.f, en2 = 0.f;
        #pragma unroll
        for (int r = 0; r < 4; ++r) {
            int t0 = g * 4 + r;
            float ev = ed[t0];
            dot = fmaf(acc0[r], ev, dot);
            cn2 = fmaf(acc0[r], acc0[r], cn2);
            en2 = fmaf(ev, ev, en2);
            int t1 = 16 + g * 4 + r;
            float ev1 = (t1 < TT) ? ed[t1] : 0.f;
            dot = fmaf(acc1[r], ev1, dot);
            cn2 = fmaf(acc1[r], acc1[r], cn2);
            en2 = fmaf(ev1, ev1, en2);
        }
        dot += __shfl_xor(dot, 16, 64); cn2 += __shfl_xor(cn2, 16, 64); en2 += __shfl_xor(en2, 16, 64);
        dot += __shfl_xor(dot, 32, 64); cn2 += __shfl_xor(cn2, 32, 64); en2 += __shfl_xor(en2, 32, 64);
        float R = dot / fmaxf(sqrtf(cn2) * sqrtf(en2), 1e-8f);
        float y = 5.0f * R;
        if (y > mrun) { srun = srun * __expf(mrun - y) + 1.f; mrun = y; }
        else          { srun += __expf(y - mrun); }
    }

    // LSE: wave butterfly (each d duplicated 4x within a wave), then cross-wave
    #pragma unroll
    for (int mk = 1; mk <= 32; mk <<= 1) {
        float mo = __shfl_xor(mrun, mk, 64);
        float so = __shfl_xor(srun, mk, 64);
        float mn = fmaxf(mrun, mo);
        srun = srun * __expf(mrun - mn) + so * __expf(mo - mn);
        mrun = mn;
    }
    // reuse alpha LDS for the 8-float cross-wave scratch (alpha no longer needed)
    float* redm = (float*)alpha;       // [4]
    float* reds = (float*)alpha + 4;   // [4]
    __syncthreads();                   // all waves done reading a2
    if (lane == 0) { redm[wave] = mrun; reds[wave] = srun; }
    __syncthreads();
    if (tid == 0) {
        float mt = fmaxf(fmaxf(redm[0], redm[1]), fmaxf(redm[2], redm[3]));
        float st = 0.f;
        #pragma unroll
        for (int w = 0; w < 4; ++w) st += reds[w] * __expf(redm[w] - mt);
        float lse = mt + logf(st * 0.25f);   // /4 removes lane-quad duplication
        Smat[bid] = powf(lse, 0.2f);
    }
}

// out[0..63] = sum_j S[i][j]; out[64..127] = sum_i S[i][j]
__global__ void reduce_kernel(const float* __restrict__ Smat, float* __restrict__ out) {
    int k = threadIdx.x;   // 0..127
    float s = 0.f;
    if (k < 64) {
        int i = k;
        for (int j = 0; j < BB; ++j) s += Smat[j * 64 + i];
        out[i] = s;
    } else {
        int jq = k - 64;
        for (int i = 0; i < BB; ++i) s += Smat[jq * 64 + i];
        out[64 + jq] = s;
    }
}

extern "C" void kernel_launch(void* const* d_in, const int* in_sizes, int n_in,
                              void* d_out, int out_size, void* d_ws, size_t ws_size,
                              hipStream_t stream) {
    const float* e = (const float*)d_in[0];
    const float* v = (const float*)d_in[1];
    float* out = (float*)d_out;
    char* ws = (char*)d_ws;
    __hip_bfloat16* eT  = (__hip_bfloat16*)(ws + ET_OFF);
    __hip_bfloat16* vT  = (__hip_bfloat16*)(ws + VT_OFF);
    __hip_bfloat16* vbf = (__hip_bfloat16*)(ws + VBF_OFF);
    float* Smat = (float*)(ws + SMAT_OFF);

    conv_e_kernel<<<64, 256, 0, stream>>>(e, eT);
    conv_v_kernel<<<512, 256, 0, stream>>>(v, vT, vbf);
    pair_kernel<<<BB * BB, 256, 0, stream>>>(e, eT, vT, vbf, Smat);
    reduce_kernel<<<1, 128, 0, stream>>>(Smat, out);
}

// Round 4
// 246.817 us; speedup vs baseline: 1.5664x; 1.5664x over previous
//
#include <hip/hip_runtime.h>
#include <hip/hip_bf16.h>
#include <math.h>

#define BB 64
#define DD 256
#define TT 24
#define NR 289

typedef float f32x4 __attribute__((ext_vector_type(4)));
typedef short bf16x8 __attribute__((ext_vector_type(8)));

// ws layout (bytes)
#define ET_OFF   0ul                     // eT  [64][32][256] bf16 (t>=24 zero)   1,048,576
#define VT_OFF   1048576ul               // vT  [64][304][256] bf16 (n>=289 zero) 9,961,472
#define VBF_OFF  11010048ul              // vbf [64][256][320] bf16 (n>=289 zero) 10,485,760
#define SMAT_OFF 21495808ul              // Smat [4096] f32

// ---- convert e -> eT[i][t][d] bf16, rows t>=24 zeroed
__global__ void conv_e_kernel(const float* __restrict__ e, __hip_bfloat16* __restrict__ eT) {
    int i = blockIdx.x, d = threadIdx.x;
    const float* src = e + ((size_t)i * DD + d) * TT;
    __hip_bfloat16* dst = eT + (size_t)i * 32 * DD + d;
    #pragma unroll
    for (int t = 0; t < 32; ++t) {
        float vv = (t < TT) ? src[t] : 0.f;
        dst[(size_t)t * DD] = __float2bfloat16(vv);
    }
}

// ---- convert v -> vT[j][n][d] and vbf[j][d][n] (both bf16, padded with zeros)
__global__ __launch_bounds__(256) void conv_v_kernel(const float* __restrict__ v,
                                                     __hip_bfloat16* __restrict__ vT,
                                                     __hip_bfloat16* __restrict__ vbf) {
    __shared__ float ld[32][305];   // pitch 305: coprime with 32 -> conflict-free col reads
    int j = blockIdx.x >> 3;
    int dbase = (blockIdx.x & 7) * 32;
    int tid = threadIdx.x;
    const float* vj = v + (size_t)j * DD * NR;
    for (int r = 0; r < 32; ++r) {
        const float* row = vj + (size_t)(dbase + r) * NR;
        ld[r][tid] = row[tid];
        if (tid < 48) {
            int n = 256 + tid;
            ld[r][n] = (n < NR) ? row[n] : 0.f;
        }
    }
    __syncthreads();
    { // vT[j][n][dbase+d], coalesced 32-lane writes
        int d = tid & 31, ng = tid >> 5;
        __hip_bfloat16* base = vT + (size_t)j * 304 * DD + dbase + d;
        for (int n = ng; n < 304; n += 8)
            base[(size_t)n * DD] = __float2bfloat16(ld[d][n]);
    }
    { // vbf[j][dbase+r][n], coalesced
        __hip_bfloat16* base = vbf + ((size_t)j * DD + dbase) * 320;
        for (int idx = tid; idx < 32 * 320; idx += 256) {
            int r = idx / 320, n = idx - r * 320;
            float vv = (n < NR) ? ld[r][n] : 0.f;
            base[(size_t)r * 320 + n] = __float2bfloat16(vv);
        }
    }
}

// ---- one block per (i,j) pair; Smat[j*64+i] = S[i][j]
// LDS = exactly 20480 B -> 8 blocks/CU possible; launch_bounds(256,4) keeps the
// VGPR cap at 128 so nothing spills (round-3 lesson: (256,8) -> 64-reg cap ->
// 348 MB of scratch writes per dispatch).
__global__ __launch_bounds__(256, 4) void pair_kernel(const float* __restrict__ e,
                                                      const __hip_bfloat16* __restrict__ eT,
                                                      const __hip_bfloat16* __restrict__ vT,
                                                      const __hip_bfloat16* __restrict__ vbf,
                                                      float* __restrict__ Smat) {
    __shared__ __align__(16) __hip_bfloat16 alpha[32 * 320];   // 20480 B, XOR-swizzled rows

    const int tid = threadIdx.x;
    const int wave = tid >> 6, lane = tid & 63;
    const int c = lane & 15, g = lane >> 4;
    const int bid = blockIdx.x;
    const int i = bid & 63, j = bid >> 6;

    char* ab = (char*)alpha;

    // zero whole buffer (pad rows 24..31 and cols >=289 must be 0 for GEMM2)
    {
        uint32_t* az = (uint32_t*)alpha;
        #pragma unroll
        for (int q = 0; q < 20; ++q) az[tid + q * 256] = 0u;
    }
    __syncthreads();

    // ================= GEMM1: s[t][n] = sum_d eT[i][t][d] * v[j][d][n] ==========
    const bf16x8* eA = (const bf16x8*)(eT + (size_t)i * 32 * DD);
    bf16x8 a1[2][8];
    #pragma unroll
    for (int m = 0; m < 2; ++m)
        #pragma unroll
        for (int k = 0; k < 8; ++k)
            a1[m][k] = eA[(m * 16 + c) * 32 + k * 4 + g];

    const bf16x8* vB = (const bf16x8*)(vT + (size_t)j * 304 * DD);
    for (int nt = wave; nt < 19; nt += 4) {
        bf16x8 b1[8];
        #pragma unroll
        for (int k = 0; k < 8; ++k)
            b1[k] = vB[(nt * 16 + c) * 32 + k * 4 + g];
        f32x4 acc0 = {0.f, 0.f, 0.f, 0.f}, acc1 = {0.f, 0.f, 0.f, 0.f};
        #pragma unroll
        for (int k = 0; k < 8; ++k) {
            acc0 = __builtin_amdgcn_mfma_f32_16x16x32_bf16(a1[0][k], b1[k], acc0, 0, 0, 0);
            acc1 = __builtin_amdgcn_mfma_f32_16x16x32_bf16(a1[1][k], b1[k], acc1, 0, 0, 0);
        }
        // store scores as bf16 into the swizzled alpha buffer
        #pragma unroll
        for (int r = 0; r < 4; ++r) {
            int t0 = g * 4 + r;
            int b0 = ((t0 * 320 + nt * 16 + c) * 2) ^ ((t0 & 7) << 4);
            *(__hip_bfloat16*)(ab + b0) = __float2bfloat16(acc0[r]);
            int t1 = 16 + g * 4 + r;
            if (t1 < TT) {
                int b1o = ((t1 * 320 + nt * 16 + c) * 2) ^ ((t1 & 7) << 4);
                *(__hip_bfloat16*)(ab + b1o) = __float2bfloat16(acc1[r]);
            }
        }
    }
    __syncthreads();

    // ============ softmax over n, in place on bf16 rows (wave owns 6 t-rows) ====
    #pragma unroll
    for (int tt = 0; tt < 6; ++tt) {
        int t = wave * 6 + tt;
        int base = t * 640, sw = (t & 7) << 4;
        float vls[5];
        #pragma unroll
        for (int k5 = 0; k5 < 5; ++k5) {
            int n = k5 * 64 + lane;
            vls[k5] = (n < NR)
                ? __bfloat162float(*(const __hip_bfloat16*)(ab + ((base + 2 * n) ^ sw)))
                : -INFINITY;
        }
        float m = vls[0];
        #pragma unroll
        for (int k5 = 1; k5 < 5; ++k5) m = fmaxf(m, vls[k5]);
        #pragma unroll
        for (int mk = 32; mk >= 1; mk >>= 1) m = fmaxf(m, __shfl_xor(m, mk, 64));
        float sum = 0.f;
        #pragma unroll
        for (int k5 = 0; k5 < 5; ++k5) { vls[k5] = __expf(vls[k5] - m); sum += vls[k5]; }
        #pragma unroll
        for (int mk = 32; mk >= 1; mk >>= 1) sum += __shfl_xor(sum, mk, 64);
        float inv = 1.f / sum;
        #pragma unroll
        for (int k5 = 0; k5 < 5; ++k5) {
            int n = k5 * 64 + lane;
            if (n < NR)
                *(__hip_bfloat16*)(ab + ((base + 2 * n) ^ sw)) = __float2bfloat16(vls[k5] * inv);
        }
    }
    __syncthreads();

    // ====== softmax over t of G1*s_norm, in place per column (thread <-> n) =====
    for (int p = 0; p < 2; ++p) {
        int n = p * 256 + tid;
        if (n < NR) {
            float vals[TT];
            #pragma unroll
            for (int t = 0; t < TT; ++t)
                vals[t] = __bfloat162float(
                    *(const __hip_bfloat16*)(ab + ((t * 640 + 2 * n) ^ ((t & 7) << 4))));
            float m = vals[0];
            #pragma unroll
            for (int t = 1; t < TT; ++t) m = fmaxf(m, vals[t]);
            m *= 4.0f;
            float sum = 0.f;
            #pragma unroll
            for (int t = 0; t < TT; ++t) { vals[t] = __expf(4.0f * vals[t] - m); sum += vals[t]; }
            float inv = 1.f / sum;
            #pragma unroll
            for (int t = 0; t < TT; ++t)
                *(__hip_bfloat16*)(ab + ((t * 640 + 2 * n) ^ ((t & 7) << 4))) =
                    __float2bfloat16(vals[t] * inv);
        }
    }
    __syncthreads();

    // ====== GEMM2: c[t][d] = sum_n alpha[t][n]*v[d][n]; fused epilogue ==========
    bf16x8 a2[2][10];
    {
        #pragma unroll
        for (int m = 0; m < 2; ++m) {
            int t = m * 16 + c;
            int sw = (t & 7) << 4;
            #pragma unroll
            for (int k = 0; k < 10; ++k) {
                int boff = (t * 640 + k * 64 + g * 16) ^ sw;
                a2[m][k] = *(const bf16x8*)(ab + boff);
            }
        }
    }
    const bf16x8* vB2 = (const bf16x8*)(vbf + (size_t)j * DD * 320);
    const float* ei = e + (size_t)i * DD * TT;

    float mrun = -INFINITY, srun = 0.f;
    for (int q = 0; q < 4; ++q) {
        int nt = wave + q * 4;   // d-tile
        bf16x8 b2[10];
        #pragma unroll
        for (int k = 0; k < 10; ++k)
            b2[k] = vB2[(nt * 16 + c) * 40 + k * 4 + g];
        f32x4 acc0 = {0.f, 0.f, 0.f, 0.f}, acc1 = {0.f, 0.f, 0.f, 0.f};
        #pragma unroll
        for (int k = 0; k < 10; ++k) {
            acc0 = __builtin_amdgcn_mfma_f32_16x16x32_bf16(a2[0][k], b2[k], acc0, 0, 0, 0);
            acc1 = __builtin_amdgcn_mfma_f32_16x16x32_bf16(a2[1][k], b2[k], acc1, 0, 0, 0);
        }
        // epilogue: cosine over t for this lane's d column
        int d = nt * 16 + c;
        const float* ed = ei + d * TT;
        float dot = 0.f, cn2 = 0.f, en2 = 0.f;
        #pragma unroll
        for (int r = 0; r < 4; ++r) {
            int t0 = g * 4 + r;
            float ev = ed[t0];
            dot = fmaf(acc0[r], ev, dot);
            cn2 = fmaf(acc0[r], acc0[r], cn2);
            en2 = fmaf(ev, ev, en2);
            int t1 = 16 + g * 4 + r;
            float ev1 = (t1 < TT) ? ed[t1] : 0.f;
            dot = fmaf(acc1[r], ev1, dot);
            cn2 = fmaf(acc1[r], acc1[r], cn2);
            en2 = fmaf(ev1, ev1, en2);
        }
        dot += __shfl_xor(dot, 16, 64); cn2 += __shfl_xor(cn2, 16, 64); en2 += __shfl_xor(en2, 16, 64);
        dot += __shfl_xor(dot, 32, 64); cn2 += __shfl_xor(cn2, 32, 64); en2 += __shfl_xor(en2, 32, 64);
        float R = dot / fmaxf(sqrtf(cn2) * sqrtf(en2), 1e-8f);
        float y = 5.0f * R;
        if (y > mrun) { srun = srun * __expf(mrun - y) + 1.f; mrun = y; }
        else          { srun += __expf(y - mrun); }
    }

    // LSE: wave butterfly (each d duplicated 4x within a wave), then cross-wave
    #pragma unroll
    for (int mk = 1; mk <= 32; mk <<= 1) {
        float mo = __shfl_xor(mrun, mk, 64);
        float so = __shfl_xor(srun, mk, 64);
        float mn = fmaxf(mrun, mo);
        srun = srun * __expf(mrun - mn) + so * __expf(mo - mn);
        mrun = mn;
    }
    // reuse alpha LDS for the 8-float cross-wave scratch (alpha no longer needed)
    float* redm = (float*)alpha;       // [4]
    float* reds = (float*)alpha + 4;   // [4]
    __syncthreads();                   // all waves done reading a2
    if (lane == 0) { redm[wave] = mrun; reds[wave] = srun; }
    __syncthreads();
    if (tid == 0) {
        float mt = fmaxf(fmaxf(redm[0], redm[1]), fmaxf(redm[2], redm[3]));
        float st = 0.f;
        #pragma unroll
        for (int w = 0; w < 4; ++w) st += reds[w] * __expf(redm[w] - mt);
        float lse = mt + logf(st * 0.25f);   // /4 removes lane-quad duplication
        Smat[bid] = powf(lse, 0.2f);
    }
}

// out[0..63] = sum_j S[i][j]; out[64..127] = sum_i S[i][j]
__global__ void reduce_kernel(const float* __restrict__ Smat, float* __restrict__ out) {
    int k = threadIdx.x;   // 0..127
    float s = 0.f;
    if (k < 64) {
        int i = k;
        for (int j = 0; j < BB; ++j) s += Smat[j * 64 + i];
        out[i] = s;
    } else {
        int jq = k - 64;
        for (int i = 0; i < BB; ++i) s += Smat[jq * 64 + i];
        out[64 + jq] = s;
    }
}

extern "C" void kernel_launch(void* const* d_in, const int* in_sizes, int n_in,
                              void* d_out, int out_size, void* d_ws, size_t ws_size,
                              hipStream_t stream) {
    const float* e = (const float*)d_in[0];
    const float* v = (const float*)d_in[1];
    float* out = (float*)d_out;
    char* ws = (char*)d_ws;
    __hip_bfloat16* eT  = (__hip_bfloat16*)(ws + ET_OFF);
    __hip_bfloat16* vT  = (__hip_bfloat16*)(ws + VT_OFF);
    __hip_bfloat16* vbf = (__hip_bfloat16*)(ws + VBF_OFF);
    float* Smat = (float*)(ws + SMAT_OFF);

    conv_e_kernel<<<64, 256, 0, stream>>>(e, eT);
    conv_v_kernel<<<512, 256, 0, stream>>>(v, vT, vbf);
    pair_kernel<<<BB * BB, 256, 0, stream>>>(e, eT, vT, vbf, Smat);
    reduce_kernel<<<1, 128, 0, stream>>>(Smat, out);
}